// Round 3
// baseline (142.670 us; speedup 1.0000x reference)
//
#include <hip/hip_runtime.h>
#include <math.h>

// Problem constants: R=4, I=16, N=2048.
#define RDIM 4
#define IDIM 16
#define NPTS 2048
#define THREADS 256
#define ROWSB 64                    // rows per block
#define RBLOCKS (NPTS / ROWSB)      // 32
#define COLCHUNK 256
#define NCHUNKS (NPTS / COLCHUNK)   // 8
#define KSTR 40                     // shorts per staged k-vector (80 B stride, bank-friendly)

typedef __attribute__((ext_vector_type(8))) short bf16x8;
typedef __attribute__((ext_vector_type(4))) float f32x4;

__device__ __forceinline__ unsigned int f2bf(float f) {
    union { float f; unsigned int u; } v; v.f = f;
    return (v.u + 0x7FFFu + ((v.u >> 16) & 1u)) >> 16;   // RNE bf16, low 16 bits valid
}
__device__ __forceinline__ float bf2f(unsigned int h) {
    union { unsigned int u; float f; } v; v.u = h << 16; return v.f;
}
// Order-preserving float -> uint key (for uint atomicMin on possibly-negative floats)
__device__ __forceinline__ unsigned int fkey(float f) {
    union { float f; unsigned int u; } v; v.f = f;
    return (v.u & 0x80000000u) ? ~v.u : (v.u | 0x80000000u);
}
__device__ __forceinline__ float funkey(unsigned int k) {
    union { unsigned int u; float f; } v;
    v.u = (k & 0x80000000u) ? (k ^ 0x80000000u) : ~k;
    return v.f;
}

__device__ __forceinline__ void make_rot(const float* __restrict__ rotv, int pair,
                                         float& r00, float& r01, float& r02,
                                         float& r10, float& r11, float& r12,
                                         float& r20, float& r21, float& r22) {
    const float ax = rotv[pair * 3 + 0];
    const float ay = rotv[pair * 3 + 1];
    const float az = rotv[pair * 3 + 2];
    float sx, cx, sy, cy, sz, cz;
    sincosf(ax, &sx, &cx);
    sincosf(ay, &sy, &cy);
    sincosf(az, &sz, &cz);
    r00 = cy * cz;                r01 = -cy * sz;               r02 = sy;
    r10 = cx * sz + sx * sy * cz; r11 = cx * cz - sx * sy * sz; r12 = -sx * cy;
    r20 = sx * sz - cx * sy * cz; r21 = sx * cz + cx * sy * sz; r22 = cx * cy;
}

// K1: per (pair, rowblock): G = X . Y^T via split-bf16 MFMA (exact-to-fp32,
// K=12 of 32: [xh,xh,xl,xl] . [yh,yl,yh,yl]). One G serves both directions:
//   row (target)   : cham_x row-min = x2 + min_m (y2[m] - 2G)  -> completed in-block
//   col (source)   : cham_y col-min = y2 + min_n (x2[n] - 2G)  -> merged via uint atomicMin
__global__ __launch_bounds__(THREADS, 4)
void chamfer_mfma(const float* __restrict__ src,   // [4,16,2048,3]
                  const float* __restrict__ tgt,   // [16,2048,3]
                  const float* __restrict__ rotv,  // [4,16,3]
                  const float* __restrict__ trav,  // [4,16,3]
                  const float* __restrict__ scal,  // [4,16]
                  unsigned int* __restrict__ partk,// [64,2048] encoded col-min keys
                  float* __restrict__ out)         // [4,16]
{
    __shared__ alignas(16) unsigned short colk[COLCHUNK * KSTR];  // 20480 B
    __shared__ alignas(16) unsigned short rowk[ROWSB * KSTR];     // 5120 B
    __shared__ float coly2[COLCHUNK];
    __shared__ alignas(16) float rowx2[ROWSB];
    __shared__ float rowpart[4][ROWSB];

    const int pair = blockIdx.x;
    const int rb   = blockIdx.y;
    const int i    = pair & (IDIM - 1);
    const int tid  = threadIdx.x;
    const int lane = tid & 63;
    const int w    = tid >> 6;       // wave 0..3
    const int g    = lane >> 4;      // lane quad 0..3
    const int c15  = lane & 15;

    float r00, r01, r02, r10, r11, r12, r20, r21, r22;
    make_rot(rotv, pair, r00, r01, r02, r10, r11, r12, r20, r21, r22);
    const float t0 = trav[pair * 3 + 0];
    const float t1 = trav[pair * 3 + 1];
    const float t2 = trav[pair * 3 + 2];
    const float s  = scal[pair];

    const float* __restrict__ srcp = src + (size_t)pair * NPTS * 3;
    const float* __restrict__ tgtp = tgt + (size_t)i    * NPTS * 3;

    // ---- one-time: zero upper k-region of colk (bytes 24..63 of each col) ----
    {
        const uint2 z2 = make_uint2(0u, 0u);
        const uint4 z4 = make_uint4(0u, 0u, 0u, 0u);
        *(uint2*)&colk[tid * KSTR + 12] = z2;
        *(uint4*)&colk[tid * KSTR + 16] = z4;
        *(uint4*)&colk[tid * KSTR + 24] = z4;
    }

    // ---- one-time: stage A (target rows, untransformed), pattern [xh,xh,xl,xl] ----
    if (tid < ROWSB) {
        const int n = rb * ROWSB + tid;
        const float x0 = tgtp[n * 3 + 0];
        const float x1 = tgtp[n * 3 + 1];
        const float x2 = tgtp[n * 3 + 2];
        const unsigned int h0 = f2bf(x0), h1 = f2bf(x1), h2 = f2bf(x2);
        const unsigned int l0 = f2bf(x0 - bf2f(h0));
        const unsigned int l1 = f2bf(x1 - bf2f(h1));
        const unsigned int l2 = f2bf(x2 - bf2f(h2));
        // k: [h0,h1,h2, h0,h1,h2, l0,l1,l2, l0,l1,l2, 0..]
        uint4 a = make_uint4(h0 | (h1 << 16), h2 | (h0 << 16), h1 | (h2 << 16), l0 | (l1 << 16));
        *(uint4*)&rowk[tid * KSTR] = a;
        uint2 b = make_uint2(l2 | (l0 << 16), l1 | (l2 << 16));
        *(uint2*)&rowk[tid * KSTR + 8] = b;
        *(uint2*)&rowk[tid * KSTR + 12] = make_uint2(0u, 0u);
        *(uint4*)&rowk[tid * KSTR + 16] = make_uint4(0u, 0u, 0u, 0u);
        *(uint4*)&rowk[tid * KSTR + 24] = make_uint4(0u, 0u, 0u, 0u);
        rowx2[tid] = x0 * x0 + x1 * x1 + x2 * x2;
    }
    __syncthreads();

    // ---- per-wave A fragments (4 rowtiles), x2 per C/D row ----
    bf16x8 afrag[4];
    f32x4  x2v[4];
#pragma unroll
    for (int rt = 0; rt < 4; ++rt) {
        afrag[rt] = *(const bf16x8*)&rowk[(rt * 16 + c15) * KSTR + (g << 3)];
        x2v[rt]   = *(const f32x4*)&rowx2[rt * 16 + (g << 2)];
    }
    float rowmin[4][4];
#pragma unroll
    for (int rt = 0; rt < 4; ++rt)
#pragma unroll
        for (int r = 0; r < 4; ++r) rowmin[rt][r] = 3.4e38f;

    const f32x4 zero4 = {0.0f, 0.0f, 0.0f, 0.0f};

    for (int ch = 0; ch < NCHUNKS; ++ch) {
        // ---- stage 256 transformed source cols, pattern [yh,yl,yh,yl] ----
        {
            const int m = ch * COLCHUNK + tid;
            const float p0 = srcp[m * 3 + 0];
            const float p1 = srcp[m * 3 + 1];
            const float p2 = srcp[m * 3 + 2];
            const float y0 = s * fmaf(r00, p0, fmaf(r01, p1, fmaf(r02, p2, t0)));
            const float y1 = s * fmaf(r10, p0, fmaf(r11, p1, fmaf(r12, p2, t1)));
            const float y2 = s * fmaf(r20, p0, fmaf(r21, p1, fmaf(r22, p2, t2)));
            coly2[tid] = y0 * y0 + y1 * y1 + y2 * y2;
            const unsigned int h0 = f2bf(y0), h1 = f2bf(y1), h2 = f2bf(y2);
            const unsigned int l0 = f2bf(y0 - bf2f(h0));
            const unsigned int l1 = f2bf(y1 - bf2f(h1));
            const unsigned int l2 = f2bf(y2 - bf2f(h2));
            // k: [h0,h1,h2, l0,l1,l2, h0,h1,h2, l0,l1,l2, 0..]
            const unsigned int u0 = h0 | (h1 << 16);
            const unsigned int u1 = h2 | (l0 << 16);
            const unsigned int u2 = l1 | (l2 << 16);
            *(uint4*)&colk[tid * KSTR]     = make_uint4(u0, u1, u2, u0);
            *(uint2*)&colk[tid * KSTR + 8] = make_uint2(u1, u2);
        }
        __syncthreads();

        // ---- wave w: 4 col-tiles of its 64-col slice ----
#pragma unroll
        for (int t = 0; t < 4; ++t) {
            const int cl = (w << 6) + (t << 4) + c15;   // local col
            const bf16x8 bfrag = *(const bf16x8*)&colk[cl * KSTR + (g << 3)];
            const float y2c = coly2[cl];
            float mcol = 3.4e38f;
#pragma unroll
            for (int rt = 0; rt < 4; ++rt) {
                f32x4 d = __builtin_amdgcn_mfma_f32_16x16x32_bf16(afrag[rt], bfrag, zero4, 0, 0, 0);
                const float c0 = fmaf(d[0], -2.0f, x2v[rt][0]);
                const float c1 = fmaf(d[1], -2.0f, x2v[rt][1]);
                const float c2 = fmaf(d[2], -2.0f, x2v[rt][2]);
                const float c3 = fmaf(d[3], -2.0f, x2v[rt][3]);
                mcol = fminf(mcol, fminf(fminf(c0, c1), fminf(c2, c3)));
                rowmin[rt][0] = fminf(rowmin[rt][0], fmaf(d[0], -2.0f, y2c));
                rowmin[rt][1] = fminf(rowmin[rt][1], fmaf(d[1], -2.0f, y2c));
                rowmin[rt][2] = fminf(rowmin[rt][2], fmaf(d[2], -2.0f, y2c));
                rowmin[rt][3] = fminf(rowmin[rt][3], fmaf(d[3], -2.0f, y2c));
            }
            // col-min across the block's 64 rows (lane quads hold disjoint rows)
            mcol = fminf(mcol, __shfl_xor(mcol, 16, 64));
            mcol = fminf(mcol, __shfl_xor(mcol, 32, 64));
            if (lane < 16)
                atomicMin(&partk[pair * NPTS + (ch << 8) + (w << 6) + (t << 4) + lane], fkey(mcol));
        }
        __syncthreads();
    }

    // ---- finish rows: min across the 16 col-classes, then across waves ----
#pragma unroll
    for (int rt = 0; rt < 4; ++rt)
#pragma unroll
        for (int r = 0; r < 4; ++r) {
            float v = rowmin[rt][r];
            v = fminf(v, __shfl_xor(v, 1, 64));
            v = fminf(v, __shfl_xor(v, 2, 64));
            v = fminf(v, __shfl_xor(v, 4, 64));
            v = fminf(v, __shfl_xor(v, 8, 64));
            if (c15 == 0) rowpart[w][rt * 16 + (g << 2) + r] = v;
        }
    __syncthreads();
    if (tid < ROWSB) {
        float m = fminf(fminf(rowpart[0][tid], rowpart[1][tid]),
                        fminf(rowpart[2][tid], rowpart[3][tid]));
        float v = m + rowx2[tid];
#pragma unroll
        for (int off = 32; off > 0; off >>= 1)
            v += __shfl_down(v, off, 64);
        if (tid == 0) atomicAdd(&out[pair], v * (1.0f / NPTS));
    }
}

// K2: decode col-min keys, add y2 (recomputed), mean over cols -> out.
__global__ __launch_bounds__(THREADS, 4)
void chamfer_colfinish(const float* __restrict__ src,
                       const float* __restrict__ rotv,
                       const float* __restrict__ trav,
                       const float* __restrict__ scal,
                       const unsigned int* __restrict__ partk,
                       float* __restrict__ out)
{
    __shared__ float wsum[THREADS / 64];
    const int pair = blockIdx.x;
    const int tid  = threadIdx.x;

    float r00, r01, r02, r10, r11, r12, r20, r21, r22;
    make_rot(rotv, pair, r00, r01, r02, r10, r11, r12, r20, r21, r22);
    const float t0 = trav[pair * 3 + 0];
    const float t1 = trav[pair * 3 + 1];
    const float t2 = trav[pair * 3 + 2];
    const float s  = scal[pair];
    const float* __restrict__ srcp = src + (size_t)pair * NPTS * 3;

    float sum = 0.0f;
#pragma unroll
    for (int u = 0; u < NPTS / THREADS; ++u) {
        const int m = u * THREADS + tid;
        const float cmin = funkey(partk[pair * NPTS + m]);
        const float p0 = srcp[m * 3 + 0];
        const float p1 = srcp[m * 3 + 1];
        const float p2 = srcp[m * 3 + 2];
        const float y0 = s * fmaf(r00, p0, fmaf(r01, p1, fmaf(r02, p2, t0)));
        const float y1 = s * fmaf(r10, p0, fmaf(r11, p1, fmaf(r12, p2, t1)));
        const float y2 = s * fmaf(r20, p0, fmaf(r21, p1, fmaf(r22, p2, t2)));
        sum += cmin + y0 * y0 + y1 * y1 + y2 * y2;
    }
#pragma unroll
    for (int off = 32; off > 0; off >>= 1)
        sum += __shfl_down(sum, off, 64);
    if ((tid & 63) == 0) wsum[tid >> 6] = sum;
    __syncthreads();
    if (tid == 0) {
        float tot = 0.0f;
#pragma unroll
        for (int wv = 0; wv < THREADS / 64; ++wv) tot += wsum[wv];
        atomicAdd(&out[pair], tot * (1.0f / NPTS));
    }
}

extern "C" void kernel_launch(void* const* d_in, const int* in_sizes, int n_in,
                              void* d_out, int out_size, void* d_ws, size_t ws_size,
                              hipStream_t stream) {
    const float* src  = (const float*)d_in[0];
    const float* tgt  = (const float*)d_in[1];
    const float* rotv = (const float*)d_in[2];
    const float* trav = (const float*)d_in[3];
    const float* scal = (const float*)d_in[4];
    float* out = (float*)d_out;                      // [4,16]
    unsigned int* partk = (unsigned int*)d_ws;       // [64,2048] keys = 512 KB

    hipMemsetAsync(out, 0, RDIM * IDIM * sizeof(float), stream);
    hipMemsetAsync(partk, 0xFF, RDIM * IDIM * NPTS * sizeof(unsigned int), stream);  // +inf keys

    dim3 grid1(RDIM * IDIM, RBLOCKS);
    chamfer_mfma<<<grid1, THREADS, 0, stream>>>(src, tgt, rotv, trav, scal, partk, out);

    chamfer_colfinish<<<RDIM * IDIM, THREADS, 0, stream>>>(src, rotv, trav, scal, partk, out);
}

// Round 4
// 103.152 us; speedup vs baseline: 1.3831x; 1.3831x over previous
//
#include <hip/hip_runtime.h>
#include <math.h>

// Problem constants: R=4, I=16, N=2048.
#define RDIM 4
#define IDIM 16
#define NPAIR (RDIM * IDIM)
#define NPTS 2048
#define THREADS 256
#define ROWSB 64                    // rows per block
#define RBLOCKS (NPTS / ROWSB)      // 32

typedef __attribute__((ext_vector_type(8))) short bf16x8;
typedef __attribute__((ext_vector_type(4))) float f32x4;

__device__ __forceinline__ unsigned int f2bf(float f) {
    union { float f; unsigned int u; } v; v.f = f;
    return (v.u + 0x7FFFu + ((v.u >> 16) & 1u)) >> 16;   // RNE bf16 (low 16 bits)
}
__device__ __forceinline__ float bf2f(unsigned int h) {
    union { unsigned int u; float f; } v; v.u = h << 16; return v.f;
}

__device__ __forceinline__ void make_rot(const float* __restrict__ rotv, int pair,
                                         float& r00, float& r01, float& r02,
                                         float& r10, float& r11, float& r12,
                                         float& r20, float& r21, float& r22) {
    const float ax = rotv[pair * 3 + 0];
    const float ay = rotv[pair * 3 + 1];
    const float az = rotv[pair * 3 + 2];
    float sx, cx, sy, cy, sz, cz;
    sincosf(ax, &sx, &cx);
    sincosf(ay, &sy, &cy);
    sincosf(az, &sz, &cz);
    r00 = cy * cz;                r01 = -cy * sz;               r02 = sy;
    r10 = cx * sz + sx * sy * cz; r11 = cx * cz - sx * sy * sz; r12 = -sx * cy;
    r20 = sx * sz - cx * sy * cz; r21 = sx * cz + cx * sy * sz; r22 = cx * cy;
}

// Build the 16-byte B-col record: v split to bf16 hi/lo of (-2v), plus split |v|^2.
// shorts: [h0,h1,h2, l0,l1,l2, n2h,n2l]
__device__ __forceinline__ uint4 make_rec(float v0, float v1, float v2, float n2) {
    const unsigned int h0 = f2bf(-2.0f * v0);
    const unsigned int h1 = f2bf(-2.0f * v1);
    const unsigned int h2 = f2bf(-2.0f * v2);
    const unsigned int l0 = f2bf(-2.0f * v0 - bf2f(h0));
    const unsigned int l1 = f2bf(-2.0f * v1 - bf2f(h1));
    const unsigned int l2 = f2bf(-2.0f * v2 - bf2f(h2));
    const unsigned int n2h = f2bf(n2);
    const unsigned int n2l = f2bf(n2 - bf2f(n2h));
    return make_uint4(h0 | (h1 << 16), h2 | (l0 << 16), l1 | (l2 << 16), n2h | (n2l << 16));
}

// K0: precompute B-form records + squared norms for both point sets.
//   blocks 0..63   : transformed source (per pair)  -> Yb, y2f
//   blocks 64..79  : target (per i)                 -> Xb, x2f
__global__ __launch_bounds__(THREADS)
void prep(const float* __restrict__ src, const float* __restrict__ tgt,
          const float* __restrict__ rotv, const float* __restrict__ trav,
          const float* __restrict__ scal,
          uint4* __restrict__ Yb, uint4* __restrict__ Xb,
          float* __restrict__ y2f, float* __restrict__ x2f)
{
    const int b = blockIdx.x;
    const int tid = threadIdx.x;
    if (b < NPAIR) {
        const int pair = b;
        float r00, r01, r02, r10, r11, r12, r20, r21, r22;
        make_rot(rotv, pair, r00, r01, r02, r10, r11, r12, r20, r21, r22);
        const float t0 = trav[pair * 3 + 0];
        const float t1 = trav[pair * 3 + 1];
        const float t2 = trav[pair * 3 + 2];
        const float s  = scal[pair];
        const float* __restrict__ srcp = src + (size_t)pair * NPTS * 3;
#pragma unroll
        for (int u = 0; u < NPTS / THREADS; ++u) {
            const int m = u * THREADS + tid;
            const float p0 = srcp[m * 3 + 0];
            const float p1 = srcp[m * 3 + 1];
            const float p2 = srcp[m * 3 + 2];
            const float y0 = s * fmaf(r00, p0, fmaf(r01, p1, fmaf(r02, p2, t0)));
            const float y1 = s * fmaf(r10, p0, fmaf(r11, p1, fmaf(r12, p2, t1)));
            const float y2 = s * fmaf(r20, p0, fmaf(r21, p1, fmaf(r22, p2, t2)));
            const float n2 = y0 * y0 + y1 * y1 + y2 * y2;
            y2f[(size_t)pair * NPTS + m] = n2;
            Yb[(size_t)pair * NPTS + m] = make_rec(y0, y1, y2, n2);
        }
    } else {
        const int i = b - NPAIR;
        const float* __restrict__ tgtp = tgt + (size_t)i * NPTS * 3;
#pragma unroll
        for (int u = 0; u < NPTS / THREADS; ++u) {
            const int m = u * THREADS + tid;
            const float x0 = tgtp[m * 3 + 0];
            const float x1 = tgtp[m * 3 + 1];
            const float x2 = tgtp[m * 3 + 2];
            const float n2 = x0 * x0 + x1 * x1 + x2 * x2;
            x2f[(size_t)i * NPTS + m] = n2;
            Xb[(size_t)i * NPTS + m] = make_rec(x0, x1, x2, n2);
        }
    }
}

// K1: per (pair, rowblock, pass): 64 query rows vs all 2048 cols via MFMA.
//   D[n,m] = -2 q_n . v_m + |v_m|^2  (split-bf16 exact to ~1e-4)
//   row result = |q_n|^2 + min_m D[n,m]; block partial-sum -> atomicAdd.
// pass 0: rows = target x, cols = transformed y (cham_x)
// pass 1: rows = transformed y, cols = target x (cham_y)
__global__ __launch_bounds__(THREADS, 4)
void chamfer_main(const float* __restrict__ src, const float* __restrict__ tgt,
                  const float* __restrict__ rotv, const float* __restrict__ trav,
                  const float* __restrict__ scal,
                  const uint4* __restrict__ Yb, const uint4* __restrict__ Xb,
                  const float* __restrict__ y2f, const float* __restrict__ x2f,
                  float* __restrict__ out)
{
    __shared__ uint4 sB[NPTS];                              // 32 KB col records
    __shared__ alignas(16) unsigned short rowk[ROWSB * 32]; // 4 KB A records
    __shared__ float rowq2[ROWSB];
    __shared__ float rowpart[4][ROWSB];

    const int pair  = blockIdx.x;
    const int rb    = blockIdx.y;
    const int passB = blockIdx.z;
    const int i     = pair & (IDIM - 1);
    const int tid   = threadIdx.x;
    const int lane  = tid & 63;
    const int w     = tid >> 6;
    const int g     = lane >> 4;
    const int c15   = lane & 15;

    // ---- stage all 2048 col records (coalesced, 16 B/lane, conflict-free) ----
    const uint4* __restrict__ gB = (passB == 0) ? (Yb + (size_t)pair * NPTS)
                                                : (Xb + (size_t)i * NPTS);
#pragma unroll
    for (int j = 0; j < NPTS / THREADS; ++j)
        sB[j * THREADS + tid] = gB[j * THREADS + tid];

    // ---- stage A records for this block's 64 query rows ----
    if (tid < ROWSB) {
        const int n = rb * ROWSB + tid;
        float q0, q1, q2v;
        if (passB == 0) {
            const float* __restrict__ tgtp = tgt + (size_t)i * NPTS * 3;
            q0 = tgtp[n * 3 + 0]; q1 = tgtp[n * 3 + 1]; q2v = tgtp[n * 3 + 2];
            rowq2[tid] = x2f[(size_t)i * NPTS + n];
        } else {
            float r00, r01, r02, r10, r11, r12, r20, r21, r22;
            make_rot(rotv, pair, r00, r01, r02, r10, r11, r12, r20, r21, r22);
            const float t0 = trav[pair * 3 + 0];
            const float t1 = trav[pair * 3 + 1];
            const float t2 = trav[pair * 3 + 2];
            const float s  = scal[pair];
            const float* __restrict__ srcp = src + (size_t)pair * NPTS * 3;
            const float p0 = srcp[n * 3 + 0];
            const float p1 = srcp[n * 3 + 1];
            const float p2 = srcp[n * 3 + 2];
            q0  = s * fmaf(r00, p0, fmaf(r01, p1, fmaf(r02, p2, t0)));
            q1  = s * fmaf(r10, p0, fmaf(r11, p1, fmaf(r12, p2, t1)));
            q2v = s * fmaf(r20, p0, fmaf(r21, p1, fmaf(r22, p2, t2)));
            rowq2[tid] = y2f[(size_t)pair * NPTS + n];
        }
        const unsigned int h0 = f2bf(q0), h1 = f2bf(q1), h2 = f2bf(q2v);
        const unsigned int l0 = f2bf(q0 - bf2f(h0));
        const unsigned int l1 = f2bf(q1 - bf2f(h1));
        const unsigned int l2 = f2bf(q2v - bf2f(h2));
        const unsigned int one = 0x3F80u;   // bf16(1.0)
        uint4* rk = (uint4*)&rowk[tid * 32];
        // k 0-7 : [qh0,qh1,qh2, ql0,ql1,ql2, 1, 1]    x B[h,h,h,l,l,l,n2h,n2l]
        // k 8-15: [ql0,ql1,ql2, qh0,qh1,qh2, 0, 0]    x B[h,h,h,l,l,l, *,  * ]
        // k16-31: zeros (B record replicated across quads; A zeros mask it)
        rk[0] = make_uint4(h0 | (h1 << 16), h2 | (l0 << 16), l1 | (l2 << 16), one | (one << 16));
        rk[1] = make_uint4(l0 | (l1 << 16), l2 | (h0 << 16), h1 | (h2 << 16), 0u);
        rk[2] = make_uint4(0u, 0u, 0u, 0u);
        rk[3] = make_uint4(0u, 0u, 0u, 0u);
    }
    __syncthreads();

    // ---- A fragments: 4 row-tiles, held in regs for the whole block ----
    bf16x8 afrag[4];
#pragma unroll
    for (int rt = 0; rt < 4; ++rt)
        afrag[rt] = *(const bf16x8*)&rowk[(rt * 16 + c15) * 32 + (g << 3)];

    float rowmin[4][4];
#pragma unroll
    for (int rt = 0; rt < 4; ++rt)
#pragma unroll
        for (int r = 0; r < 4; ++r) rowmin[rt][r] = 3.4e38f;

    const f32x4 zero4 = {0.0f, 0.0f, 0.0f, 0.0f};
    const int cw = w << 9;                  // each wave owns 512 cols

#pragma unroll 4
    for (int t = 0; t < 32; ++t) {
        const bf16x8 bfrag = *(const bf16x8*)&sB[cw + (t << 4) + c15];
#pragma unroll
        for (int rt = 0; rt < 4; ++rt) {
            f32x4 d = __builtin_amdgcn_mfma_f32_16x16x32_bf16(afrag[rt], bfrag, zero4, 0, 0, 0);
            rowmin[rt][0] = fminf(rowmin[rt][0], d[0]);
            rowmin[rt][1] = fminf(rowmin[rt][1], d[1]);
            rowmin[rt][2] = fminf(rowmin[rt][2], d[2]);
            rowmin[rt][3] = fminf(rowmin[rt][3], d[3]);
        }
    }

    // ---- reduce row-mins: across c15 (cols within wave), then across waves ----
#pragma unroll
    for (int rt = 0; rt < 4; ++rt)
#pragma unroll
        for (int r = 0; r < 4; ++r) {
            float v = rowmin[rt][r];
            v = fminf(v, __shfl_xor(v, 1, 64));
            v = fminf(v, __shfl_xor(v, 2, 64));
            v = fminf(v, __shfl_xor(v, 4, 64));
            v = fminf(v, __shfl_xor(v, 8, 64));
            if (c15 == 0) rowpart[w][rt * 16 + (g << 2) + r] = v;
        }
    __syncthreads();
    if (tid < ROWSB) {
        const float m = fminf(fminf(rowpart[0][tid], rowpart[1][tid]),
                              fminf(rowpart[2][tid], rowpart[3][tid]));
        float v = m + rowq2[tid];
#pragma unroll
        for (int off = 32; off > 0; off >>= 1)
            v += __shfl_down(v, off, 64);
        if (tid == 0) atomicAdd(&out[pair], v * (1.0f / NPTS));
    }
}

extern "C" void kernel_launch(void* const* d_in, const int* in_sizes, int n_in,
                              void* d_out, int out_size, void* d_ws, size_t ws_size,
                              hipStream_t stream) {
    const float* src  = (const float*)d_in[0];  // [4,16,2048,3]
    const float* tgt  = (const float*)d_in[1];  // [16,2048,3]
    const float* rotv = (const float*)d_in[2];  // [4,16,3]
    const float* trav = (const float*)d_in[3];  // [4,16,3]
    const float* scal = (const float*)d_in[4];  // [4,16]
    float* out = (float*)d_out;                 // [4,16]

    // ws layout: Yb 2 MB | Xb 512 KB | y2f 512 KB | x2f 128 KB  (~3.1 MB)
    char* ws = (char*)d_ws;
    uint4* Yb  = (uint4*)ws;
    uint4* Xb  = (uint4*)(ws + (size_t)NPAIR * NPTS * 16);
    float* y2f = (float*)(ws + (size_t)(NPAIR + IDIM) * NPTS * 16);
    float* x2f = y2f + (size_t)NPAIR * NPTS;

    hipMemsetAsync(out, 0, NPAIR * sizeof(float), stream);

    prep<<<NPAIR + IDIM, THREADS, 0, stream>>>(src, tgt, rotv, trav, scal, Yb, Xb, y2f, x2f);

    dim3 grid(NPAIR, RBLOCKS, 2);
    chamfer_main<<<grid, THREADS, 0, stream>>>(src, tgt, rotv, trav, scal,
                                               Yb, Xb, y2f, x2f, out);
}

// Round 5
// 84.857 us; speedup vs baseline: 1.6813x; 1.2156x over previous
//
#include <hip/hip_runtime.h>
#include <math.h>

// Problem constants: R=4, I=16, N=2048.
#define RDIM 4
#define IDIM 16
#define NPAIR 64
#define NPTS 2048
#define THREADS 256
#define ROWSB 256                   // rows per block (64 per wave)
#define RBLK (NPTS / ROWSB)         // 8
#define TILES (NPTS / 32)           // 64 col-tiles of 32
#define SCRS 68                     // scratch row stride (floats): 68%32=4 -> low conflict, 272B 16B-aligned
#define ONEBF 0x3F80u               // bf16(1.0)

typedef __attribute__((ext_vector_type(8))) short bf16x8;
typedef __attribute__((ext_vector_type(16))) float f32x16;
typedef __attribute__((ext_vector_type(4))) float f32x4;

__device__ __forceinline__ unsigned int f2bf(float f) {
    union { float f; unsigned int u; } v; v.f = f;
    return (v.u + 0x7FFFu + ((v.u >> 16) & 1u)) >> 16;   // RNE bf16 (low 16 bits)
}
__device__ __forceinline__ float bf2f(unsigned int h) {
    union { unsigned int u; float f; } v; v.u = h << 16; return v.f;
}

__device__ __forceinline__ void make_rot(const float* __restrict__ rotv, int pair,
                                         float& r00, float& r01, float& r02,
                                         float& r10, float& r11, float& r12,
                                         float& r20, float& r21, float& r22) {
    const float ax = rotv[pair * 3 + 0];
    const float ay = rotv[pair * 3 + 1];
    const float az = rotv[pair * 3 + 2];
    float sx, cx, sy, cy, sz, cz;
    sincosf(ax, &sx, &cx);
    sincosf(ay, &sy, &cy);
    sincosf(az, &sz, &cz);
    r00 = cy * cz;                r01 = -cy * sz;               r02 = sy;
    r10 = cx * sz + sx * sy * cz; r11 = cx * cz - sx * sy * sz; r12 = -sx * cy;
    r20 = sx * sz - cx * sy * cz; r21 = sx * cz + cx * sy * sz; r22 = cx * cy;
}

// B-record (16 B, same content read by both k-halves):
//   shorts [bh0,bh1,bh2, bl0,bl1,bl2, n2h, n2l],  b = split(-2v), n2 = |v|^2
__device__ __forceinline__ uint4 brec(float v0, float v1, float v2) {
    const float b0 = -2.0f * v0, b1 = -2.0f * v1, b2 = -2.0f * v2;
    const unsigned int h0 = f2bf(b0), h1 = f2bf(b1), h2 = f2bf(b2);
    const unsigned int l0 = f2bf(b0 - bf2f(h0));
    const unsigned int l1 = f2bf(b1 - bf2f(h1));
    const unsigned int l2 = f2bf(b2 - bf2f(h2));
    const float n2 = v0 * v0 + v1 * v1 + v2 * v2;
    const unsigned int nh = f2bf(n2), nl = f2bf(n2 - bf2f(nh));
    return make_uint4(h0 | (h1 << 16), h2 | (l0 << 16), l1 | (l2 << 16), nh | (nl << 16));
}
// A-record (32 B): half0 = [qh0,qh1,qh2, ql0,ql1,ql2, 1, 0]
//                  half1 = [ql0,ql1,ql2, qh0,qh1,qh2, 0, 1]
// D = (qh+ql).(bh+bl) + 1*n2h + 1*n2l = -2 q.v + |v|^2   (exact to ~1e-5)
__device__ __forceinline__ void arec(float q0, float q1, float q2, uint4& a0, uint4& a1) {
    const unsigned int h0 = f2bf(q0), h1 = f2bf(q1), h2 = f2bf(q2);
    const unsigned int l0 = f2bf(q0 - bf2f(h0));
    const unsigned int l1 = f2bf(q1 - bf2f(h1));
    const unsigned int l2 = f2bf(q2 - bf2f(h2));
    a0 = make_uint4(h0 | (h1 << 16), h2 | (l0 << 16), l1 | (l2 << 16), ONEBF);
    a1 = make_uint4(l0 | (l1 << 16), l2 | (h0 << 16), h1 | (h2 << 16), ONEBF << 16);
}

// K0: build A/B records for both point sets.
//   blocks 0..63: transformed source (per pair) -> Yb, Ya
//   blocks 64..79: target (per i)               -> Xb, Xa
__global__ __launch_bounds__(THREADS)
void prep(const float* __restrict__ src, const float* __restrict__ tgt,
          const float* __restrict__ rotv, const float* __restrict__ trav,
          const float* __restrict__ scal,
          uint4* __restrict__ Yb, uint4* __restrict__ Ya,
          uint4* __restrict__ Xb, uint4* __restrict__ Xa)
{
    const int b = blockIdx.x;
    const int tid = threadIdx.x;
    if (b < NPAIR) {
        const int pair = b;
        float r00, r01, r02, r10, r11, r12, r20, r21, r22;
        make_rot(rotv, pair, r00, r01, r02, r10, r11, r12, r20, r21, r22);
        const float t0 = trav[pair * 3 + 0];
        const float t1 = trav[pair * 3 + 1];
        const float t2 = trav[pair * 3 + 2];
        const float s  = scal[pair];
        const float* __restrict__ srcp = src + (size_t)pair * NPTS * 3;
#pragma unroll
        for (int u = 0; u < NPTS / THREADS; ++u) {
            const int m = u * THREADS + tid;
            const float p0 = srcp[m * 3 + 0];
            const float p1 = srcp[m * 3 + 1];
            const float p2 = srcp[m * 3 + 2];
            const float y0 = s * fmaf(r00, p0, fmaf(r01, p1, fmaf(r02, p2, t0)));
            const float y1 = s * fmaf(r10, p0, fmaf(r11, p1, fmaf(r12, p2, t1)));
            const float y2 = s * fmaf(r20, p0, fmaf(r21, p1, fmaf(r22, p2, t2)));
            Yb[(size_t)pair * NPTS + m] = brec(y0, y1, y2);
            uint4 a0, a1;
            arec(y0, y1, y2, a0, a1);
            Ya[((size_t)pair * NPTS + m) * 2 + 0] = a0;
            Ya[((size_t)pair * NPTS + m) * 2 + 1] = a1;
        }
    } else {
        const int i = b - NPAIR;
        const float* __restrict__ tgtp = tgt + (size_t)i * NPTS * 3;
#pragma unroll
        for (int u = 0; u < NPTS / THREADS; ++u) {
            const int m = u * THREADS + tid;
            const float x0 = tgtp[m * 3 + 0];
            const float x1 = tgtp[m * 3 + 1];
            const float x2 = tgtp[m * 3 + 2];
            Xb[(size_t)i * NPTS + m] = brec(x0, x1, x2);
            uint4 a0, a1;
            arec(x0, x1, x2, a0, a1);
            Xa[((size_t)i * NPTS + m) * 2 + 0] = a0;
            Xa[((size_t)i * NPTS + m) * 2 + 1] = a1;
        }
    }
}

// K1: per (pair, rowblock, pass). Each wave owns 64 rows x all 2048 cols.
// 32x32x16 MFMA, 1 fmin per dist-eval, LDS-transpose endgame (no shuffles).
__global__ __launch_bounds__(THREADS, 3)
void chamfer_main(const uint4* __restrict__ Yb, const uint4* __restrict__ Ya,
                  const uint4* __restrict__ Xb, const uint4* __restrict__ Xa,
                  float* __restrict__ out)
{
    // smem layout: [0, 34816): sB (32 KB, loop) / scratch (34.8 KB, endgame overlay)
    //              [34816, 43008): sA (8 KB, survives both phases)
    __shared__ alignas(16) unsigned char smem[34816 + 8192];
    __shared__ float wsum[4];
    unsigned short* sB = (unsigned short*)smem;           // [2048][8] shorts
    float* scratch = (float*)smem;                        // [4][32][SCRS]
    unsigned short* sA = (unsigned short*)(smem + 34816); // [256][16] shorts

    const int pair  = blockIdx.x;
    const int rb    = blockIdx.y;
    const int passB = blockIdx.z;  // 0: rows=target, cols=transformed; 1: swapped
    const int i     = pair & (IDIM - 1);
    const int tid   = threadIdx.x;
    const int lane  = tid & 63;
    const int w     = tid >> 6;
    const int c31   = lane & 31;
    const int h     = lane >> 5;

    const uint4* __restrict__ gB = (passB == 0) ? (Yb + (size_t)pair * NPTS)
                                                : (Xb + (size_t)i * NPTS);
    const uint4* __restrict__ gA = (passB == 0)
        ? (Xa + ((size_t)i * NPTS + rb * ROWSB) * 2)
        : (Ya + ((size_t)pair * NPTS + rb * ROWSB) * 2);

    // ---- stage: sB 2048x16B (8 uint4/thread), sA 256x32B (2 uint4/thread) ----
#pragma unroll
    for (int j = 0; j < 8; ++j)
        ((uint4*)sB)[j * THREADS + tid] = gB[j * THREADS + tid];
    ((uint4*)sA)[tid] = gA[tid];
    ((uint4*)sA)[THREADS + tid] = gA[THREADS + tid];
    __syncthreads();

    // ---- A fragments: wave w's rows [w*64, w*64+64), 2 row-tiles of 32 ----
    bf16x8 af[2];
    af[0] = *(const bf16x8*)&sA[(w * 64 + c31) * 16 + h * 8];
    af[1] = *(const bf16x8*)&sA[(w * 64 + 32 + c31) * 16 + h * 8];

    float mn[2][16];
#pragma unroll
    for (int rt = 0; rt < 2; ++rt)
#pragma unroll
        for (int j = 0; j < 16; ++j) mn[rt][j] = 3.4e38f;

    const f32x16 zero16 = {0,0,0,0, 0,0,0,0, 0,0,0,0, 0,0,0,0};

    // ---- main loop: 64 col-tiles; bfrag identical for both k-halves (broadcast) ----
#pragma unroll 4
    for (int t = 0; t < TILES; ++t) {
        const bf16x8 bf = *(const bf16x8*)&sB[(t * 32 + c31) * 8];
        const f32x16 d0 = __builtin_amdgcn_mfma_f32_32x32x16_bf16(af[0], bf, zero16, 0, 0, 0);
        const f32x16 d1 = __builtin_amdgcn_mfma_f32_32x32x16_bf16(af[1], bf, zero16, 0, 0, 0);
#pragma unroll
        for (int j = 0; j < 16; ++j) {
            mn[0][j] = fminf(mn[0][j], d0[j]);
            mn[1][j] = fminf(mn[1][j], d1[j]);
        }
    }
    __syncthreads();   // done with sB; scratch overlays it

    // ---- endgame: LDS transpose. acc reg j of tile rt -> local row rt*32+8*(j>>2)+4*h+(j&3)
    // scratch[w][c31][row] (stride SCRS), 4-consecutive-row groups -> ds_write_b128
#pragma unroll
    for (int rt = 0; rt < 2; ++rt)
#pragma unroll
        for (int g2 = 0; g2 < 4; ++g2) {
            const int rowb = rt * 32 + 8 * g2 + 4 * h;
            f32x4 v4;
            v4[0] = mn[rt][g2 * 4 + 0];
            v4[1] = mn[rt][g2 * 4 + 1];
            v4[2] = mn[rt][g2 * 4 + 2];
            v4[3] = mn[rt][g2 * 4 + 3];
            *(f32x4*)&scratch[(w * 32 + c31) * SCRS + rowb] = v4;
        }
    __syncthreads();

    // ---- thread t = block-row t: min across 32 col-classes, add |q|^2, block-sum ----
    float m = scratch[(w * 32) * SCRS + lane];
#pragma unroll
    for (int c = 1; c < 32; ++c)
        m = fminf(m, scratch[(w * 32 + c) * SCRS + lane]);

    const unsigned short* ar = &sA[tid * 16];   // half0: [qh0,qh1,qh2, ql0,ql1,ql2, ...]
    const float q0 = bf2f(ar[0]) + bf2f(ar[3]);
    const float q1 = bf2f(ar[1]) + bf2f(ar[4]);
    const float q2 = bf2f(ar[2]) + bf2f(ar[5]);
    float v = m + q0 * q0 + q1 * q1 + q2 * q2;

#pragma unroll
    for (int off = 32; off > 0; off >>= 1)
        v += __shfl_down(v, off, 64);
    if (lane == 0) wsum[w] = v;
    __syncthreads();
    if (tid == 0) {
        const float tot = wsum[0] + wsum[1] + wsum[2] + wsum[3];
        atomicAdd(&out[pair], tot * (1.0f / NPTS));
    }
}

extern "C" void kernel_launch(void* const* d_in, const int* in_sizes, int n_in,
                              void* d_out, int out_size, void* d_ws, size_t ws_size,
                              hipStream_t stream) {
    const float* src  = (const float*)d_in[0];  // [4,16,2048,3]
    const float* tgt  = (const float*)d_in[1];  // [16,2048,3]
    const float* rotv = (const float*)d_in[2];  // [4,16,3]
    const float* trav = (const float*)d_in[3];  // [4,16,3]
    const float* scal = (const float*)d_in[4];  // [4,16]
    float* out = (float*)d_out;                 // [4,16]

    // ws: Yb 2 MB | Ya 4 MB | Xb 0.5 MB | Xa 1 MB  = 7.5 MB
    char* ws = (char*)d_ws;
    uint4* Yb = (uint4*)ws;
    uint4* Ya = (uint4*)(ws + (size_t)NPAIR * NPTS * 16);
    uint4* Xb = (uint4*)(ws + (size_t)NPAIR * NPTS * 48);
    uint4* Xa = (uint4*)(ws + (size_t)NPAIR * NPTS * 48 + (size_t)IDIM * NPTS * 16);

    hipMemsetAsync(out, 0, NPAIR * sizeof(float), stream);

    prep<<<NPAIR + IDIM, THREADS, 0, stream>>>(src, tgt, rotv, trav, scal, Yb, Ya, Xb, Xa);

    dim3 grid(NPAIR, RBLK, 2);
    chamfer_main<<<grid, THREADS, 0, stream>>>(Yb, Ya, Xb, Xa, out);
}